// Round 2
// baseline (488.433 us; speedup 1.0000x reference)
//
#include <hip/hip_runtime.h>
#include <hip/hip_bf16.h>
#include <hip/hip_cooperative_groups.h>

namespace cg = cooperative_groups;

// GCN forward, bf16-MFMA + bf16 intermediates + XCD m-striping + BK=64 XOR-swizzle.
//   H1 = F @ W1                  (bf16 MFMA, bf16 out, stride 1024)
//   X1 = relu(agg(H1)+b1)        (bf16 gather-agg, bf16 out padded to 1024)
//   H2 = X1 @ W2                 (bf16 MFMA, bf16 out, stride 512)
//   out = relu(relu(agg(H2)+b2) @ W3 + b3)   (fused agg+layer3)
// R2: 6 dispatches total (was 12) — prep fuses cast+both transposes; the whole
//     CSR build is ONE cooperative kernel (zero+count+scan+fill) running after
//     gemm1 so its arrays overlay the dead W1T region; H1/H2 rows padded to
//     2048/1024 B so every gather is exactly cache-line aligned.

#define N_NODES 20000
#define N_EDGES 200000
#define D_IN    1433
#define D_H1    1000
#define D_H2    500
#define D_OUT   7

#define MPAD    20096        // 157 * 128
#define K1PAD   1472         // D_IN padded to mult of 64
#define N1PAD   1024
#define K2PAD   1024
#define N2PAD   512
#define H1STR   1024         // 2048-B rows: aligned 16-line gathers
#define H2STR   512          // 1024-B rows
#define MBLK    157          // m-blocks of 128
#define SCAN_N  (N_NODES + 1)
#define CSR_NB  20
#define CSR_T   (CSR_NB * 1024)
#define TB1     ((N1PAD / 32) * (K1PAD / 32))   // 1472 transpose blocks for W1
#define TB2     ((N2PAD / 32) * (K2PAD / 32))   // 512 for W2

typedef __attribute__((ext_vector_type(8))) short short8;
typedef __attribute__((ext_vector_type(8))) unsigned short ushort8_t;
typedef __attribute__((ext_vector_type(4))) float f32x4;

__device__ __forceinline__ unsigned short bf16_rne(float x) {
    unsigned int u = __float_as_uint(x);
    u = (u + 0x7FFFu + ((u >> 16) & 1u)) >> 16;
    return (unsigned short)u;
}
__device__ __forceinline__ float bf16_up(unsigned short h) {
    return __uint_as_float((unsigned int)h << 16);
}

__device__ __forceinline__ void gl_lds16(const unsigned short* g, unsigned short* lds) {
    __builtin_amdgcn_global_load_lds(
        (const __attribute__((address_space(1))) unsigned int*)g,
        (__attribute__((address_space(3))) unsigned int*)lds, 16, 0, 0);
}

// ---------------- prep: feature cast + W1/W2 transpose-cast, one launch
// blocks [0,MPAD): cast F rows to bf16 (K1PAD-padded)
// blocks [MPAD, MPAD+TB1): transpose W1 -> W1T[N1PAD][K1PAD]
// blocks [MPAD+TB1, MPAD+TB1+TB2): transpose W2 -> W2T[N2PAD][K2PAD]
__global__ __launch_bounds__(256) void prep(const float* __restrict__ F,
                                            unsigned int* __restrict__ Fout,
                                            const float* __restrict__ W1,
                                            unsigned short* __restrict__ W1T,
                                            const float* __restrict__ W2,
                                            unsigned short* __restrict__ W2T) {
    __shared__ float tile[32][33];
    const int bid = blockIdx.x, t = threadIdx.x;
    if (bid < MPAD) {
        const float* fr = F + (size_t)bid * D_IN;
        bool live = bid < N_NODES;
        for (int kk = t; kk < K1PAD / 2; kk += 256) {
            int k0 = kk * 2;
            float a = (live && k0     < D_IN) ? fr[k0]     : 0.f;
            float b = (live && k0 + 1 < D_IN) ? fr[k0 + 1] : 0.f;
            Fout[(size_t)bid * (K1PAD / 2) + kk] =
                (unsigned int)bf16_rne(a) | ((unsigned int)bf16_rne(b) << 16);
        }
        return;
    }
    const float* src; unsigned short* dst;
    int SR, SC, DR, DC, bx, by;
    if (bid < MPAD + TB1) {
        int l = bid - MPAD;
        bx = l % (N1PAD / 32); by = l / (N1PAD / 32);
        src = W1; dst = W1T; SR = D_IN; SC = D_H1; DR = N1PAD; DC = K1PAD;
    } else {
        int l = bid - MPAD - TB1;
        bx = l % (N2PAD / 32); by = l / (N2PAD / 32);
        src = W2; dst = W2T; SR = D_H1; SC = D_H2; DR = N2PAD; DC = K2PAD;
    }
    const int c0 = bx * 32, r0 = by * 32;
    const int tx = t & 31, ty = t >> 5;
    #pragma unroll
    for (int p = 0; p < 4; ++p) {
        int r = r0 + ty + p * 8, c = c0 + tx;
        tile[ty + p * 8][tx] = (r < SR && c < SC) ? src[(size_t)r * SC + c] : 0.f;
    }
    __syncthreads();
    #pragma unroll
    for (int p = 0; p < 4; ++p) {
        int dr = c0 + ty + p * 8;
        int dc = r0 + tx;
        if (dr < DR && dc < DC) dst[(size_t)dr * DC + dc] = bf16_rne(tile[tx][ty + p * 8]);
    }
}

// ---------------- csr_build: zero + degree-count + scan + fill, cooperative
// 20 blocks x 1024 threads (all co-resident). Phases separated by grid.sync():
//   0: zero offs   1: atomic degree count (int4 edge loads, 4 indep atomics)
//   2: per-block inclusive scan (kept in regs)  3: add block prefix, write
//      offs+cursor   4: fill srcs via cursor atomics (4-unrolled for ILP)
__global__ __launch_bounds__(1024) void csr_build(const int* __restrict__ src,
                                                  const int* __restrict__ dst,
                                                  int* __restrict__ offs,
                                                  int* __restrict__ cursor,
                                                  int* __restrict__ srcs,
                                                  int* __restrict__ bsum) {
    cg::grid_group grid = cg::this_grid();
    __shared__ int wsum[16];
    const int t = threadIdx.x, bid = blockIdx.x;
    const int tid = bid * 1024 + t;

    if (tid < SCAN_N) offs[tid] = 0;
    grid.sync();

    const int4* dst4 = (const int4*)dst;
    const int4* src4 = (const int4*)src;
    for (int q = tid; q * 4 < N_EDGES; q += CSR_T) {
        int4 d = dst4[q];
        atomicAdd(&offs[d.x + 1], 1);
        atomicAdd(&offs[d.y + 1], 1);
        atomicAdd(&offs[d.z + 1], 1);
        atomicAdd(&offs[d.w + 1], 1);
    }
    grid.sync();

    const int lane = t & 63, wv = t >> 6;
    int v = (tid < SCAN_N) ? offs[tid] : 0;
    #pragma unroll
    for (int s = 1; s < 64; s <<= 1) {
        int u = __shfl_up(v, s, 64);
        if (lane >= s) v += u;
    }
    if (lane == 63) wsum[wv] = v;
    __syncthreads();
    int prefix = 0;
    for (int k = 0; k < wv; ++k) prefix += wsum[k];
    v += prefix;
    if (t == 1023) bsum[bid] = v;
    grid.sync();

    int add = 0;
    for (int k = 0; k < bid; ++k) add += bsum[k];
    v += add;
    if (tid < SCAN_N) offs[tid] = v;
    if (tid < N_NODES) cursor[tid] = v;
    grid.sync();

    for (int q = tid; q * 4 < N_EDGES; q += CSR_T) {
        int4 d = dst4[q];
        int4 s = src4[q];
        int p0 = atomicAdd(&cursor[d.x], 1);
        int p1 = atomicAdd(&cursor[d.y], 1);
        int p2 = atomicAdd(&cursor[d.z], 1);
        int p3 = atomicAdd(&cursor[d.w], 1);
        srcs[p0] = s.x; srcs[p1] = s.y; srcs[p2] = s.z; srcs[p3] = s.w;
    }
}

// -------------------------------------------------------------- bf16 MFMA GEMM
// C[M,NPAD](bf16, stride OSTR==NB*128) = A[MPAD,KPAD] @ B^T rows[NPAD,KPAD].
// XCD m-striping: xcd = bid&7 owns m-blocks {xcd, xcd+8, ...} -> A fetched once
// chip-wide. Single LDS buffer, BK=64, 8-slot XOR swizzle. All NPAD columns are
// written (B pad rows are zero -> acc==0 there) so downstream 16B gathers may
// read the full padded row without masking.
template <int KPAD, int NB>
__global__ __launch_bounds__(256) void gemm_mfma(const unsigned short* __restrict__ A,
                                                 const unsigned short* __restrict__ B,
                                                 unsigned short* __restrict__ C,
                                                 int M, int OSTR) {
    __shared__ __align__(16) unsigned short sA[128 * 64];
    __shared__ __align__(16) unsigned short sB[128 * 64];
    const int bid = blockIdx.x;
    const int xcd = bid & 7;
    const int tt  = bid >> 3;
    const int nb  = tt % NB;
    const int mb  = (tt / NB) * 8 + xcd;
    if (mb >= MBLK) return;

    const int t = threadIdx.x;
    const int w = t >> 6, lane = t & 63;
    const int m0 = mb * 128, n0 = nb * 128;
    const int wm = (w >> 1) * 64, wn = (w & 1) * 64;

    const int srowo = lane >> 3;                       // row offset in 8-row group
    const int skc   = ((lane & 7) ^ srowo) * 8;        // XOR-swizzled global k-chunk
    const int mrow = lane & 15, quad = lane >> 4;

    const unsigned short* Aptr = A + (size_t)(m0 + srowo) * KPAD + skc;
    const unsigned short* Bptr = B + (size_t)(n0 + srowo) * KPAD + skc;

    f32x4 acc[4][4] = {};

    for (int k0 = 0; k0 < KPAD; k0 += 64) {
        #pragma unroll
        for (int c = 0; c < 4; ++c) {
            const int rbase = c * 32 + w * 8;          // 8-aligned
            gl_lds16(Aptr + (size_t)rbase * KPAD, &sA[rbase * 64]);
            gl_lds16(Bptr + (size_t)rbase * KPAD, &sB[rbase * 64]);
        }
        Aptr += 64; Bptr += 64;
        __syncthreads();

        #pragma unroll
        for (int s = 0; s < 2; ++s) {
            short8 af[4], bf[4];
            #pragma unroll
            for (int mt = 0; mt < 4; ++mt) {
                int r = wm + mt * 16 + mrow;
                af[mt] = *(const short8*)&sA[r * 64 + (((s * 4 + quad) ^ (mrow & 7)) * 8)];
            }
            #pragma unroll
            for (int nt = 0; nt < 4; ++nt) {
                int r = wn + nt * 16 + mrow;
                bf[nt] = *(const short8*)&sB[r * 64 + (((s * 4 + quad) ^ (mrow & 7)) * 8)];
            }
            #pragma unroll
            for (int mt = 0; mt < 4; ++mt)
                #pragma unroll
                for (int nt = 0; nt < 4; ++nt)
                    acc[mt][nt] = __builtin_amdgcn_mfma_f32_16x16x32_bf16(
                        af[mt], bf[nt], acc[mt][nt], 0, 0, 0);
        }
        __syncthreads();
    }

    // C/D layout: col = lane&15, row = quad*4 + reg
    #pragma unroll
    for (int mt = 0; mt < 4; ++mt) {
        int m = m0 + wm + mt * 16 + quad * 4;
        #pragma unroll
        for (int nt = 0; nt < 4; ++nt) {
            int n = n0 + wn + nt * 16 + mrow;
            #pragma unroll
            for (int r = 0; r < 4; ++r)
                if (m + r < M) C[(size_t)(m + r) * OSTR + n] = bf16_rne(acc[mt][nt][r]);
        }
    }
}

// -------------------------------- agg1: X1 = relu(agg(H1)+b1), bf16 -> bf16
// grid = MPAD: blocks >= N_NODES emit zero pad rows. 8-deep edge unroll keeps
// 8 independent 16B gathers in flight per lane. Rows are 2048 B aligned: each
// edge gather touches exactly 16 cache lines.
__global__ __launch_bounds__(128) void agg1_bf16(const unsigned short* __restrict__ H,
                                                 const int* __restrict__ offs,
                                                 const int* __restrict__ srcs,
                                                 const float* __restrict__ bias,
                                                 unsigned short* __restrict__ X) {
    const int i = blockIdx.x, t = threadIdx.x;
    const bool active = t < 125;
    const int tc = active ? t : 124;
    ushort8_t o = (ushort8_t)0;
    if (i < N_NODES) {
        const int beg = offs[i], end = offs[i + 1];
        const unsigned short* Hc = H + tc * 8;
        float s[8] = {};
        int e = beg;
        for (; e + 8 <= end; e += 8) {
            int j0 = srcs[e],     j1 = srcs[e + 1], j2 = srcs[e + 2], j3 = srcs[e + 3];
            int j4 = srcs[e + 4], j5 = srcs[e + 5], j6 = srcs[e + 6], j7 = srcs[e + 7];
            ushort8_t v0 = *(const ushort8_t*)(Hc + (size_t)j0 * H1STR);
            ushort8_t v1 = *(const ushort8_t*)(Hc + (size_t)j1 * H1STR);
            ushort8_t v2 = *(const ushort8_t*)(Hc + (size_t)j2 * H1STR);
            ushort8_t v3 = *(const ushort8_t*)(Hc + (size_t)j3 * H1STR);
            ushort8_t v4 = *(const ushort8_t*)(Hc + (size_t)j4 * H1STR);
            ushort8_t v5 = *(const ushort8_t*)(Hc + (size_t)j5 * H1STR);
            ushort8_t v6 = *(const ushort8_t*)(Hc + (size_t)j6 * H1STR);
            ushort8_t v7 = *(const ushort8_t*)(Hc + (size_t)j7 * H1STR);
            #pragma unroll
            for (int u = 0; u < 8; ++u) {
                float t0 = (bf16_up(v0[u]) + bf16_up(v1[u])) +
                           (bf16_up(v2[u]) + bf16_up(v3[u]));
                float t1 = (bf16_up(v4[u]) + bf16_up(v5[u])) +
                           (bf16_up(v6[u]) + bf16_up(v7[u]));
                s[u] += t0 + t1;
            }
        }
        for (; e + 4 <= end; e += 4) {
            int j0 = srcs[e], j1 = srcs[e + 1], j2 = srcs[e + 2], j3 = srcs[e + 3];
            ushort8_t v0 = *(const ushort8_t*)(Hc + (size_t)j0 * H1STR);
            ushort8_t v1 = *(const ushort8_t*)(Hc + (size_t)j1 * H1STR);
            ushort8_t v2 = *(const ushort8_t*)(Hc + (size_t)j2 * H1STR);
            ushort8_t v3 = *(const ushort8_t*)(Hc + (size_t)j3 * H1STR);
            #pragma unroll
            for (int u = 0; u < 8; ++u)
                s[u] += (bf16_up(v0[u]) + bf16_up(v1[u])) +
                        (bf16_up(v2[u]) + bf16_up(v3[u]));
        }
        for (; e < end; ++e) {
            ushort8_t v = *(const ushort8_t*)(Hc + (size_t)srcs[e] * H1STR);
            #pragma unroll
            for (int u = 0; u < 8; ++u) s[u] += bf16_up(v[u]);
        }
        if (active) {
            #pragma unroll
            for (int u = 0; u < 8; ++u)
                o[u] = bf16_rne(fmaxf(s[u] + bias[t * 8 + u], 0.f));
        }
    }
    *(ushort8_t*)(X + (size_t)i * K2PAD + t * 8) = o;
}

// ---------------- agg2 + layer3: out = relu(relu(agg(H2)+b2) @ W3 + b3)
// 64 lanes x 16B gather; rows 1024 B aligned. Lane 62 spans cols 496..503
// (500..503 zero pad from gemm2); lane 63 clamps to 62 (contributes 0).
__global__ __launch_bounds__(64) void agg2_out(const unsigned short* __restrict__ H,
                                               const int* __restrict__ offs,
                                               const int* __restrict__ srcs,
                                               const float* __restrict__ b2,
                                               const float* __restrict__ W3,
                                               const float* __restrict__ b3,
                                               float* __restrict__ out) {
    const int i = blockIdx.x, t = threadIdx.x;
    const int tc = t < 63 ? t : 62;
    const int beg = offs[i], end = offs[i + 1];
    const unsigned short* Hc = H + tc * 8;
    float s[8] = {};
    int e = beg;
    for (; e + 8 <= end; e += 8) {
        int j0 = srcs[e],     j1 = srcs[e + 1], j2 = srcs[e + 2], j3 = srcs[e + 3];
        int j4 = srcs[e + 4], j5 = srcs[e + 5], j6 = srcs[e + 6], j7 = srcs[e + 7];
        ushort8_t v0 = *(const ushort8_t*)(Hc + (size_t)j0 * H2STR);
        ushort8_t v1 = *(const ushort8_t*)(Hc + (size_t)j1 * H2STR);
        ushort8_t v2 = *(const ushort8_t*)(Hc + (size_t)j2 * H2STR);
        ushort8_t v3 = *(const ushort8_t*)(Hc + (size_t)j3 * H2STR);
        ushort8_t v4 = *(const ushort8_t*)(Hc + (size_t)j4 * H2STR);
        ushort8_t v5 = *(const ushort8_t*)(Hc + (size_t)j5 * H2STR);
        ushort8_t v6 = *(const ushort8_t*)(Hc + (size_t)j6 * H2STR);
        ushort8_t v7 = *(const ushort8_t*)(Hc + (size_t)j7 * H2STR);
        #pragma unroll
        for (int u = 0; u < 8; ++u) {
            float t0 = (bf16_up(v0[u]) + bf16_up(v1[u])) +
                       (bf16_up(v2[u]) + bf16_up(v3[u]));
            float t1 = (bf16_up(v4[u]) + bf16_up(v5[u])) +
                       (bf16_up(v6[u]) + bf16_up(v7[u]));
            s[u] += t0 + t1;
        }
    }
    for (; e + 4 <= end; e += 4) {
        int j0 = srcs[e], j1 = srcs[e + 1], j2 = srcs[e + 2], j3 = srcs[e + 3];
        ushort8_t v0 = *(const ushort8_t*)(Hc + (size_t)j0 * H2STR);
        ushort8_t v1 = *(const ushort8_t*)(Hc + (size_t)j1 * H2STR);
        ushort8_t v2 = *(const ushort8_t*)(Hc + (size_t)j2 * H2STR);
        ushort8_t v3 = *(const ushort8_t*)(Hc + (size_t)j3 * H2STR);
        #pragma unroll
        for (int u = 0; u < 8; ++u)
            s[u] += (bf16_up(v0[u]) + bf16_up(v1[u])) +
                    (bf16_up(v2[u]) + bf16_up(v3[u]));
    }
    for (; e < end; ++e) {
        ushort8_t v = *(const ushort8_t*)(Hc + (size_t)srcs[e] * H2STR);
        #pragma unroll
        for (int u = 0; u < 8; ++u) s[u] += bf16_up(v[u]);
    }

    float acc[D_OUT] = {};
    if (t < 63) {
        #pragma unroll
        for (int u = 0; u < 8; ++u) {
            int col = t * 8 + u;
            if (col < D_H2) {
                float x = fmaxf(s[u] + b2[col], 0.f);
                const float* wr = W3 + (size_t)col * D_OUT;
                #pragma unroll
                for (int j = 0; j < D_OUT; ++j) acc[j] += x * wr[j];
            }
        }
    }
    #pragma unroll
    for (int j = 0; j < D_OUT; ++j)
        #pragma unroll
        for (int off = 32; off; off >>= 1) acc[j] += __shfl_down(acc[j], off);
    if (t == 0) {
        #pragma unroll
        for (int j = 0; j < D_OUT; ++j)
            out[(size_t)i * D_OUT + j] = fmaxf(acc[j] + b3[j], 0.f);
    }
}

// ---------------------------------------------------------------------- launch
extern "C" void kernel_launch(void* const* d_in, const int* in_sizes, int n_in,
                              void* d_out, int out_size, void* d_ws, size_t ws_size,
                              hipStream_t stream) {
    const float* features = (const float*)d_in[0];
    const int*   src      = (const int*)d_in[1];
    const int*   dst      = (const int*)d_in[2];
    const float* W1       = (const float*)d_in[3];
    const float* b1       = (const float*)d_in[4];
    const float* W2       = (const float*)d_in[5];
    const float* b2       = (const float*)d_in[6];
    const float* W3       = (const float*)d_in[7];
    const float* b3       = (const float*)d_in[8];
    float* out = (float*)d_out;

    char* ws = (char*)d_ws;
    unsigned short* Fbf  = (unsigned short*)(ws + 0);          // [MPAD][K1PAD]   59,162,624 B
    unsigned short* X1bf = (unsigned short*)(ws + 0);          // [MPAD][K2PAD]   (overlay, after gemm1)
    unsigned short* H1   = (unsigned short*)(ws + 59162624);   // [20000][H1STR]  40,960,000 B
    unsigned short* H2   = (unsigned short*)(ws + 59162624);   // [20000][H2STR]  (overlay, after agg1)
    unsigned short* W1T  = (unsigned short*)(ws + 100122624);  // [N1PAD][K1PAD]   3,014,656 B (dead after gemm1)
    unsigned short* W2T  = (unsigned short*)(ws + 103137280);  // [N2PAD][K2PAD]   1,048,576 B
    // CSR arrays overlay the W1T region — csr_build runs AFTER gemm1:
    int* offs   = (int*)(ws + 100122624);                      // [N_NODES+1]
    int* cursor = (int*)(ws + 100202752);                      // [N_NODES]
    int* bsum   = (int*)(ws + 100282752);                      // [CSR_NB]
    int* srcs   = (int*)(ws + 100282880);                      // [N_EDGES] -> ends 101,082,880

    // 1. prep: feature cast + both weight transposes
    prep<<<MPAD + TB1 + TB2, 256, 0, stream>>>(
        features, (unsigned int*)Fbf, W1, W1T, W2, W2T);

    // 2. layer 1 GEMM: H1 = F @ W1 (frees W1T region for CSR arrays)
    gemm_mfma<K1PAD, N1PAD / 128><<<8 * (N1PAD / 128) * 20, 256, 0, stream>>>(
        Fbf, W1T, H1, N_NODES, N1PAD);

    // 3. CSR build (cooperative: zero + count + scan + fill in one dispatch)
    void* cargs[] = {(void*)&src, (void*)&dst, (void*)&offs,
                     (void*)&cursor, (void*)&srcs, (void*)&bsum};
    hipLaunchCooperativeKernel((void*)csr_build, dim3(CSR_NB), dim3(1024),
                               cargs, 0, stream);

    // 4. X1 = relu(agg(H1)+b1) (pad rows zeroed in-kernel; overlays Fbf)
    agg1_bf16<<<MPAD, 128, 0, stream>>>(H1, offs, srcs, b1, X1bf);

    // 5. layer 2 GEMM: H2 = X1 @ W2 (overlays H1)
    gemm_mfma<K2PAD, N2PAD / 128><<<8 * (N2PAD / 128) * 20, 256, 0, stream>>>(
        X1bf, W2T, H2, N_NODES, N2PAD);

    // 6. fused agg2 + layer3
    agg2_out<<<N_NODES, 64, 0, stream>>>(H2, offs, srcs, b2, W3, b3, out);
}

// Round 3
// 419.325 us; speedup vs baseline: 1.1648x; 1.1648x over previous
//
#include <hip/hip_runtime.h>
#include <hip/hip_bf16.h>

// GCN forward, bf16-MFMA + bf16 intermediates + XCD m-striping + BK=64 XOR-swizzle.
//   H1 = F @ W1                  (bf16 MFMA, bf16 out, stride 1024)
//   X1 = relu(agg(H1)+b1)        (bf16 gather-agg, bf16 out padded to 1024)
//   H2 = X1 @ W2                 (bf16 MFMA, bf16 out, stride 512)
//   out = relu(relu(agg(H2)+b2) @ W3 + b3)   (fused agg+layer3)
// R3: revert R2's cooperative csr_build (80us, 20-block latency-bound — launch
//     gaps are ~1-2us under graph capture, so consolidation never paid).
//     CSR = memset + count-fused-in-prep + ONE single-block reg-scan + wide
//     fill. cursor[] eliminated (fill advances offs in place; post-fill
//     offs[i]==O[i+1], aggs read beg=offs[i-1]). srcs overlays dead W1T
//     (fill runs after gemm1) so the aligned H1STR=1024 layout stays under
//     the proven 104.5 MB workspace footprint.

#define N_NODES 20000
#define N_EDGES 200000
#define D_IN    1433
#define D_H1    1000
#define D_H2    500
#define D_OUT   7

#define MPAD    20096        // 157 * 128
#define K1PAD   1472         // D_IN padded to mult of 64
#define N1PAD   1024
#define K2PAD   1024
#define N2PAD   512
#define H1STR   1024         // 2048-B rows: aligned 16-line gathers
#define H2STR   512          // 1024-B rows
#define MBLK    157          // m-blocks of 128
#define SCAN_N  (N_NODES + 1)
#define TB1     ((N1PAD / 32) * (K1PAD / 32))   // 1472 transpose blocks for W1
#define TB2     ((N2PAD / 32) * (K2PAD / 32))   // 512 for W2
#define CNTB    ((N_EDGES + 255) / 256)         // 782 edge-count blocks

typedef __attribute__((ext_vector_type(8))) short short8;
typedef __attribute__((ext_vector_type(8))) unsigned short ushort8_t;
typedef __attribute__((ext_vector_type(4))) float f32x4;

__device__ __forceinline__ unsigned short bf16_rne(float x) {
    unsigned int u = __float_as_uint(x);
    u = (u + 0x7FFFu + ((u >> 16) & 1u)) >> 16;
    return (unsigned short)u;
}
__device__ __forceinline__ float bf16_up(unsigned short h) {
    return __uint_as_float((unsigned int)h << 16);
}

__device__ __forceinline__ void gl_lds16(const unsigned short* g, unsigned short* lds) {
    __builtin_amdgcn_global_load_lds(
        (const __attribute__((address_space(1))) unsigned int*)g,
        (__attribute__((address_space(3))) unsigned int*)lds, 16, 0, 0);
}

// ---------------- prep: feature cast + degree count + W1/W2 transpose-cast
// blocks [0,MPAD): cast F rows to bf16; blocks [0,CNTB) also count one edge
// per thread into offs[dst+1] (hides under the cast's HBM traffic).
// blocks [MPAD, MPAD+TB1): transpose W1 -> W1T[N1PAD][K1PAD]
// blocks [MPAD+TB1, ...+TB2): transpose W2 -> W2T[N2PAD][K2PAD]
__global__ __launch_bounds__(256) void prep(const float* __restrict__ F,
                                            unsigned int* __restrict__ Fout,
                                            const float* __restrict__ W1,
                                            unsigned short* __restrict__ W1T,
                                            const float* __restrict__ W2,
                                            unsigned short* __restrict__ W2T,
                                            const int* __restrict__ dst,
                                            int* __restrict__ offs) {
    __shared__ float tile[32][33];
    const int bid = blockIdx.x, t = threadIdx.x;
    if (bid < MPAD) {
        int e = bid * 256 + t;
        if (e < N_EDGES) atomicAdd(&offs[dst[e] + 1], 1);
        const float* fr = F + (size_t)bid * D_IN;
        bool live = bid < N_NODES;
        for (int kk = t; kk < K1PAD / 2; kk += 256) {
            int k0 = kk * 2;
            float a = (live && k0     < D_IN) ? fr[k0]     : 0.f;
            float b = (live && k0 + 1 < D_IN) ? fr[k0 + 1] : 0.f;
            Fout[(size_t)bid * (K1PAD / 2) + kk] =
                (unsigned int)bf16_rne(a) | ((unsigned int)bf16_rne(b) << 16);
        }
        return;
    }
    const float* src; unsigned short* dstp;
    int SR, SC, DR, DC, bx, by;
    if (bid < MPAD + TB1) {
        int l = bid - MPAD;
        bx = l % (N1PAD / 32); by = l / (N1PAD / 32);
        src = W1; dstp = W1T; SR = D_IN; SC = D_H1; DR = N1PAD; DC = K1PAD;
    } else {
        int l = bid - MPAD - TB1;
        bx = l % (N2PAD / 32); by = l / (N2PAD / 32);
        src = W2; dstp = W2T; SR = D_H1; SC = D_H2; DR = N2PAD; DC = K2PAD;
    }
    const int c0 = bx * 32, r0 = by * 32;
    const int tx = t & 31, ty = t >> 5;
    #pragma unroll
    for (int p = 0; p < 4; ++p) {
        int r = r0 + ty + p * 8, c = c0 + tx;
        tile[ty + p * 8][tx] = (r < SR && c < SC) ? src[(size_t)r * SC + c] : 0.f;
    }
    __syncthreads();
    #pragma unroll
    for (int p = 0; p < 4; ++p) {
        int dr = c0 + ty + p * 8;
        int dc = r0 + tx;
        if (dr < DR && dc < DC) dstp[(size_t)dr * DC + dc] = bf16_rne(tile[tx][ty + p * 8]);
    }
}

// ---------------- scan: single-block inclusive scan of offs[0..20000]
// 1024 threads x 20 contiguous elems each (80 B = 16B-aligned, vectorizes).
// Local inclusive run in regs -> wave shfl-scan of totals -> wsum -> write.
__global__ __launch_bounds__(1024) void scan_csr(int* __restrict__ offs) {
    __shared__ int wsum[16];
    const int t = threadIdx.x, lane = t & 63, wv = t >> 6;
    const int base = t * 20;
    int v[20];
    int run = 0;
    #pragma unroll
    for (int k = 0; k < 20; ++k) {
        int i = base + k;
        int x = (i < SCAN_N) ? offs[i] : 0;
        run += x;
        v[k] = run;
    }
    const int tot = run;
    int w = tot;
    #pragma unroll
    for (int s = 1; s < 64; s <<= 1) {
        int u = __shfl_up(w, s, 64);
        if (lane >= s) w += u;
    }
    if (lane == 63) wsum[wv] = w;
    __syncthreads();
    int prefix = w - tot;                  // exclusive within wave
    for (int k = 0; k < wv; ++k) prefix += wsum[k];
    #pragma unroll
    for (int k = 0; k < 20; ++k) {
        int i = base + k;
        if (i < SCAN_N) offs[i] = prefix + v[k];
    }
}

// ---------------- fill: scatter edges into CSR using offs itself as cursor.
// Post-condition: offs[i] = O[i+1] (end offset of node i); aggs use
// beg = i ? offs[i-1] : 0, end = offs[i].
__global__ __launch_bounds__(256) void fill_csr(const int* __restrict__ src,
                                                const int* __restrict__ dst,
                                                int* __restrict__ offs,
                                                int* __restrict__ srcs) {
    int e = blockIdx.x * 256 + threadIdx.x;
    if (e < N_EDGES) {
        int pos = atomicAdd(&offs[dst[e]], 1);
        srcs[pos] = src[e];
    }
}

// -------------------------------------------------------------- bf16 MFMA GEMM
// C[M,NPAD](bf16, stride OSTR==NB*128) = A[MPAD,KPAD] @ B^T rows[NPAD,KPAD].
// XCD m-striping: xcd = bid&7 owns m-blocks {xcd, xcd+8, ...} -> A fetched once
// chip-wide. Single LDS buffer, BK=64, 8-slot XOR swizzle. All NPAD columns are
// written (B pad rows are zero -> acc==0 there) so downstream 16B gathers may
// read the full padded row without masking.
template <int KPAD, int NB>
__global__ __launch_bounds__(256) void gemm_mfma(const unsigned short* __restrict__ A,
                                                 const unsigned short* __restrict__ B,
                                                 unsigned short* __restrict__ C,
                                                 int M, int OSTR) {
    __shared__ __align__(16) unsigned short sA[128 * 64];
    __shared__ __align__(16) unsigned short sB[128 * 64];
    const int bid = blockIdx.x;
    const int xcd = bid & 7;
    const int tt  = bid >> 3;
    const int nb  = tt % NB;
    const int mb  = (tt / NB) * 8 + xcd;
    if (mb >= MBLK) return;

    const int t = threadIdx.x;
    const int w = t >> 6, lane = t & 63;
    const int m0 = mb * 128, n0 = nb * 128;
    const int wm = (w >> 1) * 64, wn = (w & 1) * 64;

    const int srowo = lane >> 3;                       // row offset in 8-row group
    const int skc   = ((lane & 7) ^ srowo) * 8;        // XOR-swizzled global k-chunk
    const int mrow = lane & 15, quad = lane >> 4;

    const unsigned short* Aptr = A + (size_t)(m0 + srowo) * KPAD + skc;
    const unsigned short* Bptr = B + (size_t)(n0 + srowo) * KPAD + skc;

    f32x4 acc[4][4] = {};

    for (int k0 = 0; k0 < KPAD; k0 += 64) {
        #pragma unroll
        for (int c = 0; c < 4; ++c) {
            const int rbase = c * 32 + w * 8;          // 8-aligned
            gl_lds16(Aptr + (size_t)rbase * KPAD, &sA[rbase * 64]);
            gl_lds16(Bptr + (size_t)rbase * KPAD, &sB[rbase * 64]);
        }
        Aptr += 64; Bptr += 64;
        __syncthreads();

        #pragma unroll
        for (int s = 0; s < 2; ++s) {
            short8 af[4], bf[4];
            #pragma unroll
            for (int mt = 0; mt < 4; ++mt) {
                int r = wm + mt * 16 + mrow;
                af[mt] = *(const short8*)&sA[r * 64 + (((s * 4 + quad) ^ (mrow & 7)) * 8)];
            }
            #pragma unroll
            for (int nt = 0; nt < 4; ++nt) {
                int r = wn + nt * 16 + mrow;
                bf[nt] = *(const short8*)&sB[r * 64 + (((s * 4 + quad) ^ (mrow & 7)) * 8)];
            }
            #pragma unroll
            for (int mt = 0; mt < 4; ++mt)
                #pragma unroll
                for (int nt = 0; nt < 4; ++nt)
                    acc[mt][nt] = __builtin_amdgcn_mfma_f32_16x16x32_bf16(
                        af[mt], bf[nt], acc[mt][nt], 0, 0, 0);
        }
        __syncthreads();
    }

    // C/D layout: col = lane&15, row = quad*4 + reg
    #pragma unroll
    for (int mt = 0; mt < 4; ++mt) {
        int m = m0 + wm + mt * 16 + quad * 4;
        #pragma unroll
        for (int nt = 0; nt < 4; ++nt) {
            int n = n0 + wn + nt * 16 + mrow;
            #pragma unroll
            for (int r = 0; r < 4; ++r)
                if (m + r < M) C[(size_t)(m + r) * OSTR + n] = bf16_rne(acc[mt][nt][r]);
        }
    }
}

// -------------------------------- agg1: X1 = relu(agg(H1)+b1), bf16 -> bf16
// grid = MPAD: blocks >= N_NODES emit zero pad rows. 8-deep edge unroll keeps
// 8 independent 16B gathers in flight per lane. Rows are 2048 B aligned: each
// edge gather touches exactly 16 cache lines.
__global__ __launch_bounds__(128) void agg1_bf16(const unsigned short* __restrict__ H,
                                                 const int* __restrict__ offs,
                                                 const int* __restrict__ srcs,
                                                 const float* __restrict__ bias,
                                                 unsigned short* __restrict__ X) {
    const int i = blockIdx.x, t = threadIdx.x;
    const bool active = t < 125;
    const int tc = active ? t : 124;
    ushort8_t o = (ushort8_t)0;
    if (i < N_NODES) {
        const int end = offs[i];
        const int beg = i ? offs[i - 1] : 0;
        const unsigned short* Hc = H + tc * 8;
        float s[8] = {};
        int e = beg;
        for (; e + 8 <= end; e += 8) {
            int j0 = srcs[e],     j1 = srcs[e + 1], j2 = srcs[e + 2], j3 = srcs[e + 3];
            int j4 = srcs[e + 4], j5 = srcs[e + 5], j6 = srcs[e + 6], j7 = srcs[e + 7];
            ushort8_t v0 = *(const ushort8_t*)(Hc + (size_t)j0 * H1STR);
            ushort8_t v1 = *(const ushort8_t*)(Hc + (size_t)j1 * H1STR);
            ushort8_t v2 = *(const ushort8_t*)(Hc + (size_t)j2 * H1STR);
            ushort8_t v3 = *(const ushort8_t*)(Hc + (size_t)j3 * H1STR);
            ushort8_t v4 = *(const ushort8_t*)(Hc + (size_t)j4 * H1STR);
            ushort8_t v5 = *(const ushort8_t*)(Hc + (size_t)j5 * H1STR);
            ushort8_t v6 = *(const ushort8_t*)(Hc + (size_t)j6 * H1STR);
            ushort8_t v7 = *(const ushort8_t*)(Hc + (size_t)j7 * H1STR);
            #pragma unroll
            for (int u = 0; u < 8; ++u) {
                float t0 = (bf16_up(v0[u]) + bf16_up(v1[u])) +
                           (bf16_up(v2[u]) + bf16_up(v3[u]));
                float t1 = (bf16_up(v4[u]) + bf16_up(v5[u])) +
                           (bf16_up(v6[u]) + bf16_up(v7[u]));
                s[u] += t0 + t1;
            }
        }
        for (; e + 4 <= end; e += 4) {
            int j0 = srcs[e], j1 = srcs[e + 1], j2 = srcs[e + 2], j3 = srcs[e + 3];
            ushort8_t v0 = *(const ushort8_t*)(Hc + (size_t)j0 * H1STR);
            ushort8_t v1 = *(const ushort8_t*)(Hc + (size_t)j1 * H1STR);
            ushort8_t v2 = *(const ushort8_t*)(Hc + (size_t)j2 * H1STR);
            ushort8_t v3 = *(const ushort8_t*)(Hc + (size_t)j3 * H1STR);
            #pragma unroll
            for (int u = 0; u < 8; ++u)
                s[u] += (bf16_up(v0[u]) + bf16_up(v1[u])) +
                        (bf16_up(v2[u]) + bf16_up(v3[u]));
        }
        for (; e < end; ++e) {
            ushort8_t v = *(const ushort8_t*)(Hc + (size_t)srcs[e] * H1STR);
            #pragma unroll
            for (int u = 0; u < 8; ++u) s[u] += bf16_up(v[u]);
        }
        if (active) {
            #pragma unroll
            for (int u = 0; u < 8; ++u)
                o[u] = bf16_rne(fmaxf(s[u] + bias[t * 8 + u], 0.f));
        }
    }
    *(ushort8_t*)(X + (size_t)i * K2PAD + t * 8) = o;
}

// ---------------- agg2 + layer3: out = relu(relu(agg(H2)+b2) @ W3 + b3)
// 64 lanes x 16B gather; rows 1024 B aligned. Lane 62 spans cols 496..503
// (500..503 zero pad from gemm2); lane 63 clamps to 62 (contributes 0).
__global__ __launch_bounds__(64) void agg2_out(const unsigned short* __restrict__ H,
                                               const int* __restrict__ offs,
                                               const int* __restrict__ srcs,
                                               const float* __restrict__ b2,
                                               const float* __restrict__ W3,
                                               const float* __restrict__ b3,
                                               float* __restrict__ out) {
    const int i = blockIdx.x, t = threadIdx.x;
    const int tc = t < 63 ? t : 62;
    const int end = offs[i];
    const int beg = i ? offs[i - 1] : 0;
    const unsigned short* Hc = H + tc * 8;
    float s[8] = {};
    int e = beg;
    for (; e + 8 <= end; e += 8) {
        int j0 = srcs[e],     j1 = srcs[e + 1], j2 = srcs[e + 2], j3 = srcs[e + 3];
        int j4 = srcs[e + 4], j5 = srcs[e + 5], j6 = srcs[e + 6], j7 = srcs[e + 7];
        ushort8_t v0 = *(const ushort8_t*)(Hc + (size_t)j0 * H2STR);
        ushort8_t v1 = *(const ushort8_t*)(Hc + (size_t)j1 * H2STR);
        ushort8_t v2 = *(const ushort8_t*)(Hc + (size_t)j2 * H2STR);
        ushort8_t v3 = *(const ushort8_t*)(Hc + (size_t)j3 * H2STR);
        ushort8_t v4 = *(const ushort8_t*)(Hc + (size_t)j4 * H2STR);
        ushort8_t v5 = *(const ushort8_t*)(Hc + (size_t)j5 * H2STR);
        ushort8_t v6 = *(const ushort8_t*)(Hc + (size_t)j6 * H2STR);
        ushort8_t v7 = *(const ushort8_t*)(Hc + (size_t)j7 * H2STR);
        #pragma unroll
        for (int u = 0; u < 8; ++u) {
            float t0 = (bf16_up(v0[u]) + bf16_up(v1[u])) +
                       (bf16_up(v2[u]) + bf16_up(v3[u]));
            float t1 = (bf16_up(v4[u]) + bf16_up(v5[u])) +
                       (bf16_up(v6[u]) + bf16_up(v7[u]));
            s[u] += t0 + t1;
        }
    }
    for (; e + 4 <= end; e += 4) {
        int j0 = srcs[e], j1 = srcs[e + 1], j2 = srcs[e + 2], j3 = srcs[e + 3];
        ushort8_t v0 = *(const ushort8_t*)(Hc + (size_t)j0 * H2STR);
        ushort8_t v1 = *(const ushort8_t*)(Hc + (size_t)j1 * H2STR);
        ushort8_t v2 = *(const ushort8_t*)(Hc + (size_t)j2 * H2STR);
        ushort8_t v3 = *(const ushort8_t*)(Hc + (size_t)j3 * H2STR);
        #pragma unroll
        for (int u = 0; u < 8; ++u)
            s[u] += (bf16_up(v0[u]) + bf16_up(v1[u])) +
                    (bf16_up(v2[u]) + bf16_up(v3[u]));
    }
    for (; e < end; ++e) {
        ushort8_t v = *(const ushort8_t*)(Hc + (size_t)srcs[e] * H2STR);
        #pragma unroll
        for (int u = 0; u < 8; ++u) s[u] += bf16_up(v[u]);
    }

    float acc[D_OUT] = {};
    if (t < 63) {
        #pragma unroll
        for (int u = 0; u < 8; ++u) {
            int col = t * 8 + u;
            if (col < D_H2) {
                float x = fmaxf(s[u] + b2[col], 0.f);
                const float* wr = W3 + (size_t)col * D_OUT;
                #pragma unroll
                for (int j = 0; j < D_OUT; ++j) acc[j] += x * wr[j];
            }
        }
    }
    #pragma unroll
    for (int j = 0; j < D_OUT; ++j)
        #pragma unroll
        for (int off = 32; off; off >>= 1) acc[j] += __shfl_down(acc[j], off);
    if (t == 0) {
        #pragma unroll
        for (int j = 0; j < D_OUT; ++j)
            out[(size_t)i * D_OUT + j] = fmaxf(acc[j] + b3[j], 0.f);
    }
}

// ---------------------------------------------------------------------- launch
extern "C" void kernel_launch(void* const* d_in, const int* in_sizes, int n_in,
                              void* d_out, int out_size, void* d_ws, size_t ws_size,
                              hipStream_t stream) {
    const float* features = (const float*)d_in[0];
    const int*   src      = (const int*)d_in[1];
    const int*   dst      = (const int*)d_in[2];
    const float* W1       = (const float*)d_in[3];
    const float* b1       = (const float*)d_in[4];
    const float* W2       = (const float*)d_in[5];
    const float* b2       = (const float*)d_in[6];
    const float* W3       = (const float*)d_in[7];
    const float* b3       = (const float*)d_in[8];
    float* out = (float*)d_out;

    char* ws = (char*)d_ws;
    unsigned short* Fbf  = (unsigned short*)(ws + 0);          // [MPAD][K1PAD]   59,162,624 B
    unsigned short* X1bf = (unsigned short*)(ws + 0);          // [MPAD][K2PAD]   (overlay, after gemm1)
    unsigned short* H1   = (unsigned short*)(ws + 59162624);   // [20000][H1STR]  40,960,000 B
    unsigned short* H2   = (unsigned short*)(ws + 59162624);   // [20000][H2STR]  (overlay, after agg1)
    unsigned short* W1T  = (unsigned short*)(ws + 100122624);  // [N1PAD][K1PAD]   3,014,656 B (dead after gemm1)
    unsigned short* W2T  = (unsigned short*)(ws + 103137280);  // [N2PAD][K2PAD]   1,048,576 B
    int* srcs   = (int*)(ws + 100122624);                      // [N_EDGES] 800,000 B, overlays W1T (filled after gemm1)
    int* offs   = (int*)(ws + 104185856);                      // [N_NODES+1] 80,004 B -> peak 104,265,860 B

    // 1. zero degree counters
    hipMemsetAsync(offs, 0, SCAN_N * sizeof(int), stream);

    // 2. prep: feature cast + degree count + both weight transposes
    prep<<<MPAD + TB1 + TB2, 256, 0, stream>>>(
        features, (unsigned int*)Fbf, W1, W1T, W2, W2T, dst, offs);

    // 3. inclusive scan of degrees -> CSR offsets (single block, reg-resident)
    scan_csr<<<1, 1024, 0, stream>>>(offs);

    // 4. layer 1 GEMM: H1 = F @ W1 (after this W1T region is dead)
    gemm_mfma<K1PAD, N1PAD / 128><<<8 * (N1PAD / 128) * 20, 256, 0, stream>>>(
        Fbf, W1T, H1, N_NODES, N1PAD);

    // 5. fill CSR adjacency into srcs (overlays W1T); offs becomes end-offsets
    fill_csr<<<CNTB, 256, 0, stream>>>(src, dst, offs, srcs);

    // 6. X1 = relu(agg(H1)+b1) (pad rows zeroed in-kernel; overlays Fbf)
    agg1_bf16<<<MPAD, 128, 0, stream>>>(H1, offs, srcs, b1, X1bf);

    // 7. layer 2 GEMM: H2 = X1 @ W2 (overlays H1)
    gemm_mfma<K2PAD, N2PAD / 128><<<8 * (N2PAD / 128) * 20, 256, 0, stream>>>(
        X1bf, W2T, H2, N_NODES, N2PAD);

    // 8. fused agg2 + layer3
    agg2_out<<<N_NODES, 64, 0, stream>>>(H2, offs, srcs, b2, W3, b3, out);
}